// Round 4
// baseline (388.198 us; speedup 1.0000x reference)
//
#include <hip/hip_runtime.h>
#include <math.h>

#define CN 128
#define SN 56
#define PCOLS 33               // A-tile cols: c0-2 .. c0+30
#define GTS 136                // Gt row stride (ushorts)
#define NQ (14 * 28)           // outputs per band
#define QSZ (NQ + 256)         // + per-thread dump slots

typedef float  fr4 __attribute__((ext_vector_type(4)));
typedef short  sh8 __attribute__((ext_vector_type(8)));

__device__ __forceinline__ unsigned short f2bf(float f) {
    unsigned u = __float_as_uint(f);
    u += 0x7FFFu + ((u >> 16) & 1u);          // RNE
    return (unsigned short)(u >> 16);
}

// pack two f32 -> bf16x2 (round half up): 2 adds + 1 v_perm
__device__ __forceinline__ int pk2(float f0, float f1) {
    unsigned u0 = __float_as_uint(f0) + 0x8000u;
    unsigned u1 = __float_as_uint(f1) + 0x8000u;
    return (int)__builtin_amdgcn_perm(u1, u0, 0x07060302u);
}

// One block per (b, c, row-half h, col-half w); two 14-row bands per block.
// GEMM T[px,128u] x G[128u,36taps] via mfma_16x16x32_bf16, A-frags generated
// in-register (t = exp2(nI*log2 x)); C-fragments scatter-accumulated straight
// into fp32 LDS Q[14x28] with ds_add_f32 (each P element feeds exactly one
// output px). No P tile, no gather loop.
__global__ __launch_bounds__(256, 4) void divnorm_mfma(
        const float* __restrict__ x, const float* __restrict__ theta,
        const float* __restrict__ pP, const float* __restrict__ sig,
        const float* __restrict__ aA, const float* __restrict__ nI,
        const float* __restrict__ nU, const float* __restrict__ bias,
        float* __restrict__ out)
{
    __shared__ alignas(16) unsigned short Gt[48 * GTS];   // [tap(pad48)][u] bf16
    __shared__ float Q[QSZ];                              // band accumulator + dumps

    const int bid = blockIdx.x;
    const int w   = bid & 1;
    const int h   = (bid >> 1) & 1;
    const int c   = (bid >> 2) & 127;
    const int b   = bid >> 9;
    const int tid = threadIdx.x;
    const int lane = tid & 63;
    const int wv   = tid >> 6;
    const int l15  = lane & 15;
    const int lg   = lane >> 4;

    // Zero Q (incl. dump slots) and Gt pad rows 36..47.
    for (int i = tid; i < QSZ; i += 256) Q[i] = 0.0f;
    for (int i = tid; i < 12 * GTS; i += 256) Gt[36 * GTS + i] = 0;

    // Gaussian bank inline: G[u, tap] -> Gt[tap][u] bf16.
    for (int idx = tid; idx < CN * 36; idx += 256) {
        int u  = idx / 36;
        int tap = idx - u * 36;
        int ky = tap / 6;
        int kx = tap - ky * 6;
        int pr = c * CN + u;
        float th = theta[pr], pv = pP[pr], sv = sig[pr], av = aA[pr];
        float ct = __cosf(th), st = __sinf(th);
        float xv = -3.0f + 1.2f * ky;
        float yv = -3.0f + 1.2f * kx;
        float xr =  xv * ct + yv * st;
        float yr = -xv * st + yv * ct;
        float e  = -0.5f * (xr * xr / (pv * pv) + yr * yr / (sv * sv));
        float g  = (av / (2.0f * 3.14159265358979323846f * pv * sv))
                   * __builtin_amdgcn_exp2f(e * 1.44269504088896341f);
        Gt[tap * GTS + u] = f2bf(g);
    }

    // Per-lane nI (A-operand multipliers): u = ks*32 + lg*8 + j.
    float nIr[4][8];
    {
        const float* nc = nI + c * CN;
        #pragma unroll
        for (int ks = 0; ks < 4; ++ks) {
            const float4* q = (const float4*)(nc + ks * 32 + lg * 8);
            float4 q0 = q[0], q1 = q[1];
            nIr[ks][0] = q0.x; nIr[ks][1] = q0.y; nIr[ks][2] = q0.z; nIr[ks][3] = q0.w;
            nIr[ks][4] = q1.x; nIr[ks][5] = q1.y; nIr[ks][6] = q1.z; nIr[ks][7] = q1.w;
        }
    }

    // Per-lane tap constants for the 3 N-tiles; pad taps (>=36) poisoned so
    // the oy-validity compare kills them for free.
    int dyc[3], dxc[3];
    #pragma unroll
    for (int nt = 0; nt < 3; ++nt) {
        int tap = nt * 16 + l15;
        dyc[nt] = (tap < 36) ? (tap / 6) : 1000;
        dxc[nt] = tap - (tap / 6) * 6;
    }

    const float* xc = x   + (size_t)(b * CN + c) * (SN * SN);
    float*       oc = out + (size_t)(b * CN + c) * (SN * SN);
    const float nUc = nU[c];
    const float bn  = __builtin_amdgcn_exp2f(nUc * __builtin_amdgcn_logf(bias[c]));
    const int   c0  = 28 * w;

    __syncthreads();

    // Preload all 12 B-frags (block-invariant): B[k = ks*32+lg*8+j][n = nt*16+l15].
    sh8 Bf[3][4];
    #pragma unroll
    for (int nt = 0; nt < 3; ++nt)
        #pragma unroll
        for (int ks = 0; ks < 4; ++ks)
            Bf[nt][ks] = *(const sh8*)&Gt[(nt * 16 + l15) * GTS + ks * 32 + lg * 8];

    #pragma unroll 1
    for (int band = 0; band < 2; ++band) {
        const int r0 = 28 * h + 14 * band;

        // ---- GEMM + scatter: 40 M-tiles of 16 px rows (wave-strided) ----
        #pragma unroll 1
        for (int mt = wv; mt < 40; mt += 4) {
            // A-row (px) for this lane.
            int pidx = mt * 16 + l15;
            int prl  = pidx / PCOLS;
            int pcl  = pidx - prl * PCOLS;
            int prow = r0 - 2 + prl;
            int pcol = c0 - 2 + pcl;
            bool vld = ((unsigned)prow < 56u) && ((unsigned)pcol < 56u);
            float xv = xc[vld ? (prow * SN + pcol) : 0];
            float L  = vld ? __builtin_amdgcn_logf(xv) : -1e30f;  // OOB -> t=0

            fr4 a0 = {0.f,0.f,0.f,0.f}, a1 = {0.f,0.f,0.f,0.f}, a2 = {0.f,0.f,0.f,0.f};
            #pragma unroll
            for (int ks = 0; ks < 4; ++ks) {
                float t[8];
                #pragma unroll
                for (int j = 0; j < 8; ++j)
                    t[j] = __builtin_amdgcn_exp2f(nIr[ks][j] * L);
                int4 ai;
                ai.x = pk2(t[0], t[1]); ai.y = pk2(t[2], t[3]);
                ai.z = pk2(t[4], t[5]); ai.w = pk2(t[6], t[7]);
                sh8 af = *(sh8*)&ai;
                a0 = __builtin_amdgcn_mfma_f32_16x16x32_bf16(af, Bf[0][ks], a0, 0, 0, 0);
                a1 = __builtin_amdgcn_mfma_f32_16x16x32_bf16(af, Bf[1][ks], a1, 0, 0, 0);
                a2 = __builtin_amdgcn_mfma_f32_16x16x32_bf16(af, Bf[2][ks], a2, 0, 0, 0);
            }

            // Scatter C: element (pi = mt*16+lg*4+r, tap = nt*16+l15) feeds
            // output (oy = prl-dy, ox = pcl-dx); invalid -> per-thread dump.
            #pragma unroll
            for (int r = 0; r < 4; ++r) {
                int pi  = mt * 16 + lg * 4 + r;
                int rl  = pi / PCOLS;
                int cl  = pi - rl * PCOLS;
                #pragma unroll
                for (int nt = 0; nt < 3; ++nt) {
                    int oy = rl - dyc[nt];
                    int ox = cl - dxc[nt];
                    bool valid = ((unsigned)oy < 14u) && ((unsigned)ox < 28u);
                    int o = valid ? (oy * 28 + ox) : (NQ + tid);
                    float v = (nt == 0) ? a0[r] : ((nt == 1) ? a1[r] : a2[r]);
                    atomicAdd(&Q[o], v);   // ds_add_f32, no return
                }
            }
        }
        __syncthreads();

        // ---- Finalize band: out = x^nU / (bias^nU + Q), re-zero Q ----
        #pragma unroll
        for (int k = 0; k < 2; ++k) {
            int pp = tid + 256 * k;
            if (pp < NQ) {
                int oy = pp / 28;
                int ox = pp - oy * 28;
                float s = Q[pp];
                Q[pp] = 0.0f;
                int y  = r0 + oy;
                int xg = c0 + ox;
                float xv  = xc[y * SN + xg];
                float num = __builtin_amdgcn_exp2f(nUc * __builtin_amdgcn_logf(xv));
                oc[y * SN + xg] = num / (bn + s);
            }
        }
        __syncthreads();
    }
}

extern "C" void kernel_launch(void* const* d_in, const int* in_sizes, int n_in,
                              void* d_out, int out_size, void* d_ws, size_t ws_size,
                              hipStream_t stream) {
    const float* x     = (const float*)d_in[0];
    const float* theta = (const float*)d_in[1];
    const float* p     = (const float*)d_in[2];
    const float* sig   = (const float*)d_in[3];
    const float* a     = (const float*)d_in[4];
    const float* nI    = (const float*)d_in[5];
    const float* nU    = (const float*)d_in[6];
    const float* bias  = (const float*)d_in[7];
    float* out = (float*)d_out;

    hipLaunchKernelGGL(divnorm_mfma, dim3(2 * CN * 4), dim3(256), 0, stream,
                       x, theta, p, sig, a, nI, nU, bias, out);
}

// Round 5
// 120.427 us; speedup vs baseline: 3.2235x; 3.2235x over previous
//
#include <hip/hip_runtime.h>
#include <math.h>

#define CN 128
#define SN 56
#define PCOLS 33               // A-tile cols: c0-2 .. c0+30
#define NPX 627                // 19 x 33 valid px slots per band
#define MT 40                  // M-tiles (40*16 = 640 >= 627)
#define PXPAD 654              // P plane stride (ushorts); /2 = 327 == 7 mod 32
#define GTS 136                // Gt row stride (ushorts) inside the union
#define DYS (6 * PXPAD + PCOLS)   // 3957: gather dy step
#define DXS (PXPAD + 1)           // 655:  gather dx step

typedef float  fr4 __attribute__((ext_vector_type(4)));
typedef short  sh8 __attribute__((ext_vector_type(8)));

__device__ __forceinline__ unsigned short f2bf(float f) {
    unsigned u = __float_as_uint(f);
    u += 0x7FFFu + ((u >> 16) & 1u);          // RNE
    return (unsigned short)(u >> 16);
}
// pack two f32 -> bf16x2 (round half up): low = f0, high = f1
__device__ __forceinline__ int pk2(float f0, float f1) {
    unsigned u0 = __float_as_uint(f0) + 0x8000u;
    unsigned u1 = __float_as_uint(f1) + 0x8000u;
    return (int)__builtin_amdgcn_perm(u1, u0, 0x07060302u);
}
__device__ __forceinline__ float bf2f(unsigned short s) {
    return __uint_as_float(((unsigned)s) << 16);
}

// One block per (b, c, row-half h, col-half w); two 14-row bands.
// GEMM P[36 taps, 627 px] = G^T x T via mfma_16x16x32_bf16 (A-frags generated
// in-register: t = exp2(nI*log2 x)); P stored TRANSPOSED [tap][px] bf16 so
// scatter is packed b32 and gather is lane-consecutive immediate-offset reads.
__global__ __launch_bounds__(256, 3) void divnorm_mfma(
        const float* __restrict__ x, const float* __restrict__ theta,
        const float* __restrict__ pP, const float* __restrict__ sig,
        const float* __restrict__ aA, const float* __restrict__ nI,
        const float* __restrict__ nU, const float* __restrict__ bias,
        float* __restrict__ out)
{
    // Union: Gt[48][GTS] (init only, 6528 ushorts) overlaps P[36][PXPAD] (23544).
    __shared__ alignas(16) unsigned short SH[36 * PXPAD];
    unsigned short* Gt = SH;

    const int bid = blockIdx.x;
    const int w   = bid & 1;
    const int h   = (bid >> 1) & 1;
    const int c   = (bid >> 2) & 127;
    const int b   = bid >> 9;
    const int tid = threadIdx.x;
    const int lane = tid & 63;
    const int wv   = tid >> 6;
    const int l15  = lane & 15;
    const int lg   = lane >> 4;

    // Zero Gt pad-tap rows 36..47 (read by B-frag preload).
    for (int i = tid; i < 12 * GTS; i += 256) Gt[36 * GTS + i] = 0;

    // Gaussian bank inline: G[u, tap] -> Gt[tap][u] bf16.
    for (int idx = tid; idx < CN * 36; idx += 256) {
        int u  = idx / 36;
        int tap = idx - u * 36;
        int ky = tap / 6;
        int kx = tap - ky * 6;
        int pr = c * CN + u;
        float th = theta[pr], pv = pP[pr], sv = sig[pr], av = aA[pr];
        float ct = __cosf(th), st = __sinf(th);
        float xv = -3.0f + 1.2f * ky;
        float yv = -3.0f + 1.2f * kx;
        float xr =  xv * ct + yv * st;
        float yr = -xv * st + yv * ct;
        float e  = -0.5f * (xr * xr / (pv * pv) + yr * yr / (sv * sv));
        float g  = (av / (2.0f * 3.14159265358979323846f * pv * sv))
                   * __builtin_amdgcn_exp2f(e * 1.44269504088896341f);
        Gt[tap * GTS + u] = f2bf(g);
    }

    // Per-lane nI (A multipliers): u = ks*32 + lg*8 + j.
    float nIr[4][8];
    {
        const float* nc = nI + c * CN;
        #pragma unroll
        for (int ks = 0; ks < 4; ++ks) {
            const float4* q = (const float4*)(nc + ks * 32 + lg * 8);
            float4 q0 = q[0], q1 = q[1];
            nIr[ks][0] = q0.x; nIr[ks][1] = q0.y; nIr[ks][2] = q0.z; nIr[ks][3] = q0.w;
            nIr[ks][4] = q1.x; nIr[ks][5] = q1.y; nIr[ks][6] = q1.z; nIr[ks][7] = q1.w;
        }
    }

    const float* xc = x   + (size_t)(b * CN + c) * (SN * SN);
    float*       oc = out + (size_t)(b * CN + c) * (SN * SN);
    const float nUc = nU[c];
    const float bn  = __builtin_amdgcn_exp2f(nUc * __builtin_amdgcn_logf(bias[c]));
    const int   c0  = 28 * w;

    __syncthreads();

    // Preload 12 B-frags (block-invariant): B[k = ks*32+lg*8+j][n = nt*16+l15].
    sh8 Bf[3][4];
    #pragma unroll
    for (int nt = 0; nt < 3; ++nt)
        #pragma unroll
        for (int ks = 0; ks < 4; ++ks)
            Bf[nt][ks] = *(const sh8*)&Gt[(nt * 16 + l15) * GTS + ks * 32 + lg * 8];
    __syncthreads();   // all B-frags read before P overwrites the union

    #pragma unroll 1
    for (int band = 0; band < 2; ++band) {
        const int r0 = 28 * h + 14 * band;

        // ---- GEMM + transposed scatter: 40 M-tiles, wave-strided ----
        #pragma unroll 1
        for (int mt = wv; mt < MT; mt += 4) {
            int pidx = mt * 16 + l15;              // A-row (px) for this lane
            int prl  = pidx / PCOLS;
            int pcl  = pidx - prl * PCOLS;
            int prow = r0 - 2 + prl;
            int pcol = c0 - 2 + pcl;
            bool vld = ((unsigned)prow < 56u) && ((unsigned)pcol < 56u);
            float xv = xc[vld ? (prow * SN + pcol) : 0];
            float L  = vld ? __builtin_amdgcn_logf(xv) : -1e30f;  // OOB -> t=0

            fr4 a0 = {0.f,0.f,0.f,0.f}, a1 = {0.f,0.f,0.f,0.f}, a2 = {0.f,0.f,0.f,0.f};
            #pragma unroll
            for (int ks = 0; ks < 4; ++ks) {
                float t[8];
                #pragma unroll
                for (int j = 0; j < 8; ++j)
                    t[j] = __builtin_amdgcn_exp2f(nIr[ks][j] * L);
                int4 ai;
                ai.x = pk2(t[0], t[1]); ai.y = pk2(t[2], t[3]);
                ai.z = pk2(t[4], t[5]); ai.w = pk2(t[6], t[7]);
                sh8 af = *(sh8*)&ai;
                a0 = __builtin_amdgcn_mfma_f32_16x16x32_bf16(af, Bf[0][ks], a0, 0, 0, 0);
                a1 = __builtin_amdgcn_mfma_f32_16x16x32_bf16(af, Bf[1][ks], a1, 0, 0, 0);
                a2 = __builtin_amdgcn_mfma_f32_16x16x32_bf16(af, Bf[2][ks], a2, 0, 0, 0);
            }

            // C (row = px = mt*16+lg*4+r, col = tap = nt*16+l15) -> P[tap][px].
            // Rows r,r+1 are adjacent px in one tap plane: pack b32.
            const int pbase = mt * 16 + lg * 4;
            #pragma unroll
            for (int nt = 0; nt < 3; ++nt) {
                int tap = nt * 16 + l15;
                if (tap < 36) {
                    fr4 av4 = (nt == 0) ? a0 : ((nt == 1) ? a1 : a2);
                    int* dst = (int*)&SH[tap * PXPAD + pbase];
                    dst[0] = pk2(av4[0], av4[1]);
                    dst[1] = pk2(av4[2], av4[3]);
                }
            }
        }
        __syncthreads();

        // ---- Gather: out = x^nU / (bias^nU + sum_tap P[tap][o0+off(tap)]) ----
        #pragma unroll
        for (int k = 0; k < 2; ++k) {
            int pp = tid + 256 * k;
            if (pp < 14 * 28) {
                int oy = pp / 28;
                int ox = pp - oy * 28;
                const unsigned short* pb = &SH[oy * PCOLS + ox];
                float s = 0.0f;
                #pragma unroll
                for (int dy = 0; dy < 6; ++dy)
                    #pragma unroll
                    for (int dx = 0; dx < 6; ++dx)
                        s += bf2f(pb[dy * DYS + dx * DXS]);
                int y  = r0 + oy;
                int xg = c0 + ox;
                float xv  = xc[y * SN + xg];
                float num = __builtin_amdgcn_exp2f(nUc * __builtin_amdgcn_logf(xv));
                oc[y * SN + xg] = num / (bn + s);
            }
        }
        __syncthreads();
    }
}

extern "C" void kernel_launch(void* const* d_in, const int* in_sizes, int n_in,
                              void* d_out, int out_size, void* d_ws, size_t ws_size,
                              hipStream_t stream) {
    const float* x     = (const float*)d_in[0];
    const float* theta = (const float*)d_in[1];
    const float* p     = (const float*)d_in[2];
    const float* sig   = (const float*)d_in[3];
    const float* a     = (const float*)d_in[4];
    const float* nI    = (const float*)d_in[5];
    const float* nU    = (const float*)d_in[6];
    const float* bias  = (const float*)d_in[7];
    float* out = (float*)d_out;

    hipLaunchKernelGGL(divnorm_mfma, dim3(2 * CN * 4), dim3(256), 0, stream,
                       x, theta, p, sig, a, nI, nU, bias, out);
}

// Round 6
// 107.463 us; speedup vs baseline: 3.6124x; 1.1206x over previous
//
#include <hip/hip_runtime.h>
#include <math.h>

#define CN 128
#define SN 56
#define PCOLS 33                  // A-tile cols: c0-2 .. c0+30
#define PXPAD 654                 // P plane stride (ushorts); /2 = 327 == 7 mod 32
#define PXPAD_DW 327
#define DYS (6 * PXPAD + PCOLS)   // 3957: gather dy step (ushorts)
#define DXS (PXPAD + 1)           // 655:  gather dx step
#define LOG2E 1.44269504088896341f

typedef float  fr4 __attribute__((ext_vector_type(4)));
typedef short  sh8 __attribute__((ext_vector_type(8)));

__device__ __forceinline__ unsigned short f2bf(float f) {
    unsigned u = __float_as_uint(f);
    u += 0x7FFFu + ((u >> 16) & 1u);          // RNE
    return (unsigned short)(u >> 16);
}
// pack two f32 -> bf16x2 (round half up): low = f0, high = f1
__device__ __forceinline__ int pk2(float f0, float f1) {
    unsigned u0 = __float_as_uint(f0) + 0x8000u;
    unsigned u1 = __float_as_uint(f1) + 0x8000u;
    return (int)__builtin_amdgcn_perm(u1, u0, 0x07060302u);
}
__device__ __forceinline__ float bf2f(unsigned short s) {
    return __uint_as_float(((unsigned)s) << 16);
}

// ---- Kernel A: Gaussian bank pre-swizzled into B-fragment order ----
// bank[c][ks][nt][lane][8 ushorts]: element j = G^T[tap = nt*16+(lane&15)]
// [u = ks*32+(lane>>4)*8+j] in bf16; tap >= 36 -> 0. One thread per lane-slot.
__global__ void bank_kernel(const float* __restrict__ theta,
                            const float* __restrict__ p,
                            const float* __restrict__ sig,
                            const float* __restrict__ a,
                            unsigned short* __restrict__ bank) {
    int t = blockIdx.x * 256 + threadIdx.x;       // < 128*4*3*64 = 98304
    int lane = t & 63;
    int grp  = t >> 6;
    int nt = grp % 3;
    int ks = (grp / 3) & 3;
    int c  = grp / 12;
    int tap = nt * 16 + (lane & 15);
    int ub  = ks * 32 + (lane >> 4) * 8;
    sh8 v = {0,0,0,0,0,0,0,0};
    if (tap < 36) {
        int ky = tap / 6, kx = tap - ky * 6;
        float xv = -3.0f + 1.2f * ky;
        float yv = -3.0f + 1.2f * kx;
        #pragma unroll
        for (int j = 0; j < 8; ++j) {
            int pr = c * CN + ub + j;
            float th = theta[pr], pv = p[pr], sv = sig[pr], av = a[pr];
            float ct = __cosf(th), st = __sinf(th);
            float xr =  xv * ct + yv * st;
            float yr = -xv * st + yv * ct;
            float e  = -0.5f * (xr * xr / (pv * pv) + yr * yr / (sv * sv));
            float g  = (av / (2.0f * 3.14159265358979323846f * pv * sv))
                       * __builtin_amdgcn_exp2f(e * LOG2E);
            v[j] = (short)f2bf(g);
        }
    }
    ((sh8*)bank)[t] = v;
}

// ---- Main kernel: one block per (b, c, h, w); 512 threads = 8 waves ----
// Two 14-row bands; per band: GEMM P[36 taps][627 px] = G^T x T via
// mfma_16x16x32_bf16 with A-frags generated in-register (t = exp2(nI*log2 x)),
// P transposed [tap][px] bf16 in LDS, then 36-tap stencil gather -> out.
__global__ __launch_bounds__(512, 4) void divnorm_mfma(
        const float* __restrict__ x, const unsigned short* __restrict__ bank,
        const float* __restrict__ nI, const float* __restrict__ nU,
        const float* __restrict__ bias, float* __restrict__ out)
{
    __shared__ alignas(16) unsigned short SH[36 * PXPAD];   // 47088 B

    const int bid = blockIdx.x;
    const int w   = bid & 1;
    const int h   = (bid >> 1) & 1;
    const int c   = (bid >> 2) & 127;
    const int b   = bid >> 9;
    const int tid = threadIdx.x;
    const int lane = tid & 63;
    const int wv   = tid >> 6;          // 0..7
    const int l15  = lane & 15;
    const int lg   = lane >> 4;

    // B-frags: 12 coalesced 16B loads from the pre-swizzled bank.
    sh8 Bf[3][4];
    {
        const sh8* bp = (const sh8*)bank + (size_t)c * 768 + lane;
        #pragma unroll
        for (int ks = 0; ks < 4; ++ks)
            #pragma unroll
            for (int nt = 0; nt < 3; ++nt)
                Bf[nt][ks] = bp[(ks * 3 + nt) * 64];
    }

    // Per-lane nI (A multipliers): u = ks*32 + lg*8 + j.
    float nIr[4][8];
    {
        const float* nc = nI + c * CN;
        #pragma unroll
        for (int ks = 0; ks < 4; ++ks) {
            const float4* q = (const float4*)(nc + ks * 32 + lg * 8);
            float4 q0 = q[0], q1 = q[1];
            nIr[ks][0] = q0.x; nIr[ks][1] = q0.y; nIr[ks][2] = q0.z; nIr[ks][3] = q0.w;
            nIr[ks][4] = q1.x; nIr[ks][5] = q1.y; nIr[ks][6] = q1.z; nIr[ks][7] = q1.w;
        }
    }

    const float* xc = x   + (size_t)(b * CN + c) * (SN * SN);
    float*       oc = out + (size_t)(b * CN + c) * (SN * SN);
    const float nUc = nU[c];
    const float bn  = __builtin_amdgcn_exp2f(nUc * __builtin_amdgcn_logf(bias[c]));
    const int   c0m2 = 28 * w - 2;

    // Scatter plane bases (dwords) for this lane's 3 taps.
    const int pof0 = l15 * PXPAD_DW;
    const int pof1 = (16 + l15) * PXPAD_DW;
    const int pof2 = (32 + l15) * PXPAD_DW;

    #pragma unroll 1
    for (int band = 0; band < 2; ++band) {
        const int r0   = 28 * h + 14 * band;
        const int r0m2 = r0 - 2;

        // ---- GEMM + transposed scatter: 5 M-tiles/wave (mt = wv + 8i) ----
        int pidx = wv * 16 + l15;
        int prl  = pidx / PCOLS;
        int pcl  = pidx - prl * PCOLS;
        int prow = r0m2 + prl;
        int pcol = c0m2 + pcl;
        bool val = ((unsigned)prow < 56u) && ((unsigned)pcol < 56u);
        float xv = xc[val ? (prow * SN + pcol) : 0];

        #pragma unroll 1
        for (int i = 0; i < 5; ++i) {
            float L = val ? __builtin_amdgcn_logf(xv) : -1e30f;   // OOB -> t=0

            // Prefetch next M-tile's x (i=4 loads a clamped dummy).
            {
                int np   = pidx + 128;
                int nprl = np / PCOLS;
                int npcl = np - nprl * PCOLS;
                int nprw = r0m2 + nprl;
                int npcc = c0m2 + npcl;
                val = ((unsigned)nprw < 56u) && ((unsigned)npcc < 56u);
                xv  = xc[val ? (nprw * SN + npcc) : 0];
                pidx = np;
            }

            fr4 a0 = {0.f,0.f,0.f,0.f}, a1 = {0.f,0.f,0.f,0.f}, a2 = {0.f,0.f,0.f,0.f};
            #pragma unroll
            for (int ks = 0; ks < 4; ++ks) {
                float t[8];
                #pragma unroll
                for (int j = 0; j < 8; ++j)
                    t[j] = __builtin_amdgcn_exp2f(nIr[ks][j] * L);
                int4 ai;
                ai.x = pk2(t[0], t[1]); ai.y = pk2(t[2], t[3]);
                ai.z = pk2(t[4], t[5]); ai.w = pk2(t[6], t[7]);
                sh8 af = *(sh8*)&ai;
                a0 = __builtin_amdgcn_mfma_f32_16x16x32_bf16(af, Bf[0][ks], a0, 0, 0, 0);
                a1 = __builtin_amdgcn_mfma_f32_16x16x32_bf16(af, Bf[1][ks], a1, 0, 0, 0);
                a2 = __builtin_amdgcn_mfma_f32_16x16x32_bf16(af, Bf[2][ks], a2, 0, 0, 0);
            }

            // C (row = px = mt*16+lg*4+r, col = tap = nt*16+l15) -> P[tap][px].
            int pbd = (wv + 8 * i) * 8 + lg * 2;     // dword px base
            int* SD = (int*)SH;
            SD[pof0 + pbd]     = pk2(a0[0], a0[1]);
            SD[pof0 + pbd + 1] = pk2(a0[2], a0[3]);
            SD[pof1 + pbd]     = pk2(a1[0], a1[1]);
            SD[pof1 + pbd + 1] = pk2(a1[2], a1[3]);
            if (l15 < 4) {                            // taps 32..35 only
                SD[pof2 + pbd]     = pk2(a2[0], a2[1]);
                SD[pof2 + pbd + 1] = pk2(a2[2], a2[3]);
            }
        }
        __syncthreads();

        // ---- Gather: out = x^nU / (bias^nU + sum_tap P[tap][px(tap)]) ----
        if (tid < 14 * 28) {
            int oy = tid / 28;
            int ox = tid - oy * 28;
            const unsigned short* pb = &SH[oy * PCOLS + ox];
            float s = 0.0f;
            #pragma unroll
            for (int dy = 0; dy < 6; ++dy)
                #pragma unroll
                for (int dx = 0; dx < 6; ++dx)
                    s += bf2f(pb[dy * DYS + dx * DXS]);
            int y  = r0 + oy;
            int xg = c0m2 + 2 + ox;
            float xq  = xc[y * SN + xg];
            float num = __builtin_amdgcn_exp2f(nUc * __builtin_amdgcn_logf(xq));
            oc[y * SN + xg] = num / (bn + s);
        }
        __syncthreads();
    }
}

extern "C" void kernel_launch(void* const* d_in, const int* in_sizes, int n_in,
                              void* d_out, int out_size, void* d_ws, size_t ws_size,
                              hipStream_t stream) {
    const float* x     = (const float*)d_in[0];
    const float* theta = (const float*)d_in[1];
    const float* p     = (const float*)d_in[2];
    const float* sig   = (const float*)d_in[3];
    const float* a     = (const float*)d_in[4];
    const float* nI    = (const float*)d_in[5];
    const float* nU    = (const float*)d_in[6];
    const float* bias  = (const float*)d_in[7];
    float* out = (float*)d_out;
    unsigned short* bank = (unsigned short*)d_ws;   // 128*768*8 ushorts = 1.57 MB

    hipLaunchKernelGGL(bank_kernel, dim3(384), dim3(256), 0, stream,
                       theta, p, sig, a, bank);
    hipLaunchKernelGGL(divnorm_mfma, dim3(2 * CN * 4), dim3(512), 0, stream,
                       x, bank, nI, nU, bias, out);
}

// Round 7
// 105.559 us; speedup vs baseline: 3.6775x; 1.0180x over previous
//
#include <hip/hip_runtime.h>
#include <math.h>

#define CN 128
#define SN 56
#define PCOLS 33                  // P plane: 19 rows x 33 cols (px = row*33+col)
#define SDW 322                   // plane stride, dwords (even, == 2 mod 32)
#define PXS 644                   // plane stride, ushorts
#define DYS (6 * PXS + PCOLS)     // 3897: gather dy step (ushorts)
#define DXS (PXS + 1)             // 645:  gather dx step
#define LOG2E 1.44269504088896341f

typedef float  fr4 __attribute__((ext_vector_type(4)));
typedef short  sh8 __attribute__((ext_vector_type(8)));

__device__ __forceinline__ unsigned short f2bf(float f) {
    unsigned u = __float_as_uint(f);
    u += 0x7FFFu + ((u >> 16) & 1u);          // RNE
    return (unsigned short)(u >> 16);
}
// pack two f32 -> bf16x2 (round half up): low = f0, high = f1
__device__ __forceinline__ int pk2(float f0, float f1) {
    unsigned u0 = __float_as_uint(f0) + 0x8000u;
    unsigned u1 = __float_as_uint(f1) + 0x8000u;
    return (int)__builtin_amdgcn_perm(u1, u0, 0x07060302u);
}
__device__ __forceinline__ float bf2f(unsigned short s) {
    return __uint_as_float(((unsigned)s) << 16);
}

// ---- Kernel A: Gaussian bank pre-swizzled into B-fragment order ----
// bank[c][ks][nt][lane][8 ushorts]: element j = G^T[tap = nt*16+(lane&15)]
// [u = ks*32+(lane>>4)*8+j] in bf16; tap >= 36 -> 0.
__global__ void bank_kernel(const float* __restrict__ theta,
                            const float* __restrict__ p,
                            const float* __restrict__ sig,
                            const float* __restrict__ a,
                            unsigned short* __restrict__ bank) {
    int t = blockIdx.x * 256 + threadIdx.x;       // < 128*4*3*64 = 98304
    int lane = t & 63;
    int grp  = t >> 6;
    int nt = grp % 3;
    int ks = (grp / 3) & 3;
    int c  = grp / 12;
    int tap = nt * 16 + (lane & 15);
    int ub  = ks * 32 + (lane >> 4) * 8;
    sh8 v = {0,0,0,0,0,0,0,0};
    if (tap < 36) {
        int ky = tap / 6, kx = tap - ky * 6;
        float xv = -3.0f + 1.2f * ky;
        float yv = -3.0f + 1.2f * kx;
        #pragma unroll
        for (int j = 0; j < 8; ++j) {
            int pr = c * CN + ub + j;
            float th = theta[pr], pv = p[pr], sv = sig[pr], av = a[pr];
            float ct = __cosf(th), st = __sinf(th);
            float xr =  xv * ct + yv * st;
            float yr = -xv * st + yv * ct;
            float e  = -0.5f * (xr * xr / (pv * pv) + yr * yr / (sv * sv));
            float g  = (av / (2.0f * 3.14159265358979323846f * pv * sv))
                       * __builtin_amdgcn_exp2f(e * LOG2E);
            v[j] = (short)f2bf(g);
        }
    }
    ((sh8*)bank)[t] = v;
}

// ---- Main kernel: one block per (b, c, h, w); 512 threads = 8 waves ----
// Two 14-row bands; P[36 taps][19x33 px] bf16 in LDS. Band 1 reuses band 0's
// overlapping 5 halo rows via an LDS plane-shift copy (GEMM does 30 tiles
// instead of 40). Gather: 36-tap stencil sum -> out.
__global__ __launch_bounds__(512, 4) void divnorm_mfma(
        const float* __restrict__ x, const unsigned short* __restrict__ bank,
        const float* __restrict__ nI, const float* __restrict__ nU,
        const float* __restrict__ bias, float* __restrict__ out)
{
    __shared__ alignas(16) unsigned short SH[36 * PXS];   // 46368 B
    int* SD = (int*)SH;

    const int bid = blockIdx.x;
    const int w   = bid & 1;
    const int h   = (bid >> 1) & 1;
    const int c   = (bid >> 2) & 127;
    const int b   = bid >> 9;
    const int tid = threadIdx.x;
    const int lane = tid & 63;
    const int wv   = tid >> 6;          // 0..7
    const int l15  = lane & 15;
    const int lg   = lane >> 4;

    // B-frags: 12 coalesced 16B loads from the pre-swizzled bank.
    sh8 Bf[3][4];
    {
        const sh8* bp = (const sh8*)bank + (size_t)c * 768 + lane;
        #pragma unroll
        for (int ks = 0; ks < 4; ++ks)
            #pragma unroll
            for (int nt = 0; nt < 3; ++nt)
                Bf[nt][ks] = bp[(ks * 3 + nt) * 64];
    }

    // Per-lane nI (A multipliers): u = ks*32 + lg*8 + j.
    float nIr[4][8];
    {
        const float* nc = nI + c * CN;
        #pragma unroll
        for (int ks = 0; ks < 4; ++ks) {
            const float4* q = (const float4*)(nc + ks * 32 + lg * 8);
            float4 q0 = q[0], q1 = q[1];
            nIr[ks][0] = q0.x; nIr[ks][1] = q0.y; nIr[ks][2] = q0.z; nIr[ks][3] = q0.w;
            nIr[ks][4] = q1.x; nIr[ks][5] = q1.y; nIr[ks][6] = q1.z; nIr[ks][7] = q1.w;
        }
    }

    const float* xc = x   + (size_t)(b * CN + c) * (SN * SN);
    float*       oc = out + (size_t)(b * CN + c) * (SN * SN);
    const float nUc = nU[c];
    const float bn  = __builtin_amdgcn_exp2f(nUc * __builtin_amdgcn_logf(bias[c]));
    const int   c0m2 = 28 * w - 2;

    // Scatter plane bases (dwords) for this lane's 3 taps (8B-aligned: SDW even).
    const int pof0 = l15 * SDW;
    const int pof1 = (16 + l15) * SDW;
    const int pof2 = (32 + l15) * SDW;

    #pragma unroll 1
    for (int phase = 0; phase < 2; ++phase) {
        const int r0   = 28 * h + 14 * phase;
        const int r0m2 = r0 - 2;
        const int tb   = phase ? 10 : 0;                    // first M-tile
        const int nit  = phase ? ((wv < 6) ? 4 : 3) : 5;    // tiles this wave

        // ---- GEMM + transposed scatter (tile = tb + wv + 8i) ----
        int pidx = (tb + wv) * 16 + l15;
        int prl  = pidx / PCOLS;
        int pcl  = pidx - prl * PCOLS;
        int prow = r0m2 + prl;
        int pcol = c0m2 + pcl;
        bool val = ((unsigned)prow < 56u) && ((unsigned)pcol < 56u);
        float xv = xc[val ? (prow * SN + pcol) : 0];

        #pragma unroll 1
        for (int i = 0; i < nit; ++i) {
            float L = val ? __builtin_amdgcn_logf(xv) : -1e30f;   // OOB -> t=0

            // Prefetch next M-tile's x (last iter loads a harmless dummy).
            {
                int np   = pidx + 128;
                int nprl = np / PCOLS;
                int npcl = np - nprl * PCOLS;
                int nprw = r0m2 + nprl;
                int npcc = c0m2 + npcl;
                val = ((unsigned)nprw < 56u) && ((unsigned)npcc < 56u);
                xv  = xc[val ? (nprw * SN + npcc) : 0];
                pidx = np;
            }

            fr4 a0 = {0.f,0.f,0.f,0.f}, a1 = {0.f,0.f,0.f,0.f}, a2 = {0.f,0.f,0.f,0.f};
            #pragma unroll
            for (int ks = 0; ks < 4; ++ks) {
                float t[8];
                #pragma unroll
                for (int j = 0; j < 8; ++j)
                    t[j] = __builtin_amdgcn_exp2f(nIr[ks][j] * L);
                int4 ai;
                ai.x = pk2(t[0], t[1]); ai.y = pk2(t[2], t[3]);
                ai.z = pk2(t[4], t[5]); ai.w = pk2(t[6], t[7]);
                sh8 af = *(sh8*)&ai;
                a0 = __builtin_amdgcn_mfma_f32_16x16x32_bf16(af, Bf[0][ks], a0, 0, 0, 0);
                a1 = __builtin_amdgcn_mfma_f32_16x16x32_bf16(af, Bf[1][ks], a1, 0, 0, 0);
                a2 = __builtin_amdgcn_mfma_f32_16x16x32_bf16(af, Bf[2][ks], a2, 0, 0, 0);
            }

            // C (px = tile*16+lg*4+r, tap = nt*16+l15) -> P[tap][px], b64 stores.
            int pbd = (tb + wv + 8 * i) * 8 + lg * 2;     // dword px base (even)
            int2 v0, v1;
            v0.x = pk2(a0[0], a0[1]); v0.y = pk2(a0[2], a0[3]);
            v1.x = pk2(a1[0], a1[1]); v1.y = pk2(a1[2], a1[3]);
            *(int2*)&SD[pof0 + pbd] = v0;
            *(int2*)&SD[pof1 + pbd] = v1;
            if (l15 < 4) {                                 // taps 32..35 only
                int2 v2;
                v2.x = pk2(a2[0], a2[1]); v2.y = pk2(a2[2], a2[3]);
                *(int2*)&SD[pof2 + pbd] = v2;
            }
        }
        __syncthreads();

        // ---- Gather: out = x^nU / (bias^nU + sum_tap P[tap][px(tap)]) ----
        if (tid < 14 * 28) {
            int oy = tid / 28;
            int ox = tid - oy * 28;
            const unsigned short* pb = &SH[oy * PCOLS + ox];
            float s = 0.0f;
            #pragma unroll
            for (int dy = 0; dy < 6; ++dy)
                #pragma unroll
                for (int dx = 0; dx < 6; ++dx)
                    s += bf2f(pb[dy * DYS + dx * DXS]);
            int y  = r0 + oy;
            int xg = c0m2 + 2 + ox;
            float xq  = xc[y * SN + xg];
            float num = __builtin_amdgcn_exp2f(nUc * __builtin_amdgcn_logf(xq));
            oc[y * SN + xg] = num / (bn + s);
        }
        __syncthreads();

        // ---- Halo share: band-0 P rows 14..18 -> band-1 rows 0..4 ----
        if (phase == 0) {
            // px 0..159 (80 dw) per plane; src = dst + 462 ush (231 dw).
            for (int idx = tid; idx < 36 * 80; idx += 512) {
                int pl  = idx / 80;
                int off = idx - pl * 80;
                SD[pl * SDW + off] = SD[pl * SDW + 231 + off];
            }
            __syncthreads();
        }
    }
}

extern "C" void kernel_launch(void* const* d_in, const int* in_sizes, int n_in,
                              void* d_out, int out_size, void* d_ws, size_t ws_size,
                              hipStream_t stream) {
    const float* x     = (const float*)d_in[0];
    const float* theta = (const float*)d_in[1];
    const float* p     = (const float*)d_in[2];
    const float* sig   = (const float*)d_in[3];
    const float* a     = (const float*)d_in[4];
    const float* nI    = (const float*)d_in[5];
    const float* nU    = (const float*)d_in[6];
    const float* bias  = (const float*)d_in[7];
    float* out = (float*)d_out;
    unsigned short* bank = (unsigned short*)d_ws;   // 128*768*8 ushorts = 1.57 MB

    hipLaunchKernelGGL(bank_kernel, dim3(384), dim3(256), 0, stream,
                       theta, p, sig, a, bank);
    hipLaunchKernelGGL(divnorm_mfma, dim3(2 * CN * 4), dim3(512), 0, stream,
                       x, bank, nI, nU, bias, out);
}